// Round 3
// baseline (223.038 us; speedup 1.0000x reference)
//
#include <hip/hip_runtime.h>
#include <math.h>

// SocialPooling: B=8, N=8192, D=64.
// weights: w_ij = exp(-d2/50) if sqrt(max(d2,1e-12)) <= 10 else 0;
//          keep w >= (32nd largest in row); normalize by clipped row sum.
// out[b,i,d] = sum_j w_ij * F[b,j,d]  -- sparse (~32 nz/row).

constexpr int MAXC = 1024;   // candidate cap (expected ~257, max ~330)
constexpr int MAXK = 64;     // kept cap (expected ~32, slack for ties)

__global__ __launch_bounds__(256)
void social_pool_kernel(const float* __restrict__ F,
                        const float* __restrict__ C,
                        float* __restrict__ out,
                        int N, int B)
{
    const int i = blockIdx.x;
    const int t = threadIdx.x;

    __shared__ float cw[MAXC];   // candidate weights
    __shared__ int   cj[MAXC];   // candidate indices
    __shared__ float cv[MAXC];   // selection scratch (destroyed)
    __shared__ float kw[MAXK];   // kept (normalized) weights
    __shared__ int   kj[MAXK];   // kept indices
    __shared__ int   s_mcount;
    __shared__ int   s_kcount;
    __shared__ float s_thresh;
    __shared__ float red_v[4];
    __shared__ int   red_i[4];

    if (t == 0) { s_mcount = 0; s_kcount = 0; s_thresh = 0.0f; }
    __syncthreads();

    const float2* C2 = (const float2*)C;
    const float2 ci = C2[i];

    // ---- pass 1: collect candidates within radius ----
    for (int j = t; j < N; j += 256) {
        float2 cp = C2[j];
        float dx = ci.x - cp.x;
        float dy = ci.y - cp.y;
        float d2 = dx * dx + dy * dy;
        // match reference exactly: d = sqrt(max(d2,1e-12)); keep if d <= 10
        float d = sqrtf(fmaxf(d2, 1e-12f));
        if (d <= 10.0f) {
            float w = expf(-(d2 / 50.0f));
            int slot = atomicAdd(&s_mcount, 1);
            if (slot < MAXC) { cw[slot] = w; cj[slot] = j; }
        }
    }
    __syncthreads();
    const int M = min(s_mcount, MAXC);

    // ---- pass 2: exact 32nd-largest via 32 max-extractions ----
    if (M > 32) {
        for (int k = t; k < M; k += 256) cv[k] = cw[k];
        __syncthreads();
        const int lane = t & 63;
        const int wave = t >> 6;
        for (int it = 0; it < 32; ++it) {
            float bv = -2.0f; int bi = -1;
            for (int k = t; k < M; k += 256) {
                float v = cv[k];
                if (v > bv) { bv = v; bi = k; }
            }
            #pragma unroll
            for (int off = 32; off > 0; off >>= 1) {
                float ov = __shfl_down(bv, off);
                int   oi = __shfl_down(bi, off);
                if (ov > bv) { bv = ov; bi = oi; }
            }
            if (lane == 0) { red_v[wave] = bv; red_i[wave] = bi; }
            __syncthreads();
            if (t == 0) {
                float mv = red_v[0]; int mi = red_i[0];
                #pragma unroll
                for (int wq = 1; wq < 4; ++wq)
                    if (red_v[wq] > mv) { mv = red_v[wq]; mi = red_i[wq]; }
                if (mi >= 0) cv[mi] = -1.0f;   // extract
                if (it == 31) s_thresh = mv;   // 32nd largest
            }
            __syncthreads();
        }
    }
    const float thresh = s_thresh;

    // ---- pass 3: compact kept entries (value-based keep => tie-correct) ----
    for (int k = t; k < M; k += 256) {
        if (cw[k] >= thresh) {
            int slot = atomicAdd(&s_kcount, 1);
            if (slot < MAXK) { kw[slot] = cw[k]; kj[slot] = cj[k]; }
        }
    }
    __syncthreads();
    const int K = min(s_kcount, MAXK);

    // ---- normalize (K ~ 32; thread 0 is fine) ----
    if (t == 0) {
        float s = 0.0f;
        for (int k = 0; k < K; ++k) s += kw[k];
        s = fmaxf(s, 1e-8f);                    // clip(sum, 1e-8, None)
        for (int k = 0; k < K; ++k) kw[k] = kw[k] / s;  // true division as ref
    }
    __syncthreads();

    // ---- pass 4: sparse pooling. thread (d, b-group) -> out[b,i,d] ----
    const int d  = t & 63;     // D == 64
    const int bo = t >> 6;     // 4 b-groups per block
    for (int b = bo; b < B; b += 4) {
        const float* Fb = F + (size_t)b * (size_t)N * 64;
        float acc = 0.0f;
        for (int k = 0; k < K; ++k) {
            acc += kw[k] * Fb[(size_t)kj[k] * 64 + d];  // 256B coalesced per (b,k)
        }
        out[((size_t)b * (size_t)N + (size_t)i) * 64 + d] = acc;
    }
}

extern "C" void kernel_launch(void* const* d_in, const int* in_sizes, int n_in,
                              void* d_out, int out_size, void* d_ws, size_t ws_size,
                              hipStream_t stream)
{
    const float* F = (const float*)d_in[0];   // features [B,N,64] f32
    const float* C = (const float*)d_in[1];   // coordinates [N,2] f32
    float* out = (float*)d_out;               // [B,N,64] f32

    const int N = in_sizes[1] / 2;            // 8192
    const int B = in_sizes[0] / (N * 64);     // 8

    social_pool_kernel<<<N, 256, 0, stream>>>(F, C, out, N, B);
}

// Round 4
// 156.515 us; speedup vs baseline: 1.4250x; 1.4250x over previous
//
#include <hip/hip_runtime.h>
#include <math.h>

// SocialPooling: B=8, N=8192, D=64.
// w_ij = exp(-d2/50) if sqrt(max(d2,1e-12)) <= 10 else 0;
// keep w >= (32nd largest in row) [value-based => tie-correct];
// normalize by clip(row_sum, 1e-8); out[b,i,d] = sum_j w_ij * F[b,j,d].
//
// R3 change: replace 32x serial max-extraction (13K cyc/block, barrier-heavy)
// with O(M^2) rank-by-counting on w (register-resident owned candidates,
// float4 broadcast LDS reads, no barriers in the hot loop).

constexpr int MAXC = 512;    // candidate cap (lambda~257, std~16 => <<512)
constexpr int MAXK = 64;     // kept cap (expected ~32, slack for ties)

__global__ __launch_bounds__(256)
void social_pool_kernel(const float* __restrict__ F,
                        const float* __restrict__ C,
                        float* __restrict__ out,
                        int N, int B)
{
    const int i = blockIdx.x;
    const int t = threadIdx.x;

    __shared__ __align__(16) float cw[MAXC];  // candidate weights
    __shared__ int   cj[MAXC];                // candidate indices
    __shared__ float kw[MAXK];                // kept (then normalized) weights
    __shared__ int   kj[MAXK];                // kept indices
    __shared__ int   s_mcount;
    __shared__ int   s_kcount;
    __shared__ float s_sum;

    if (t == 0) { s_mcount = 0; s_kcount = 0; }
    __syncthreads();

    const float2* C2 = (const float2*)C;
    const float2 ci = C2[i];

    // ---- pass 1: collect candidates within radius (identical to R2) ----
    for (int j = t; j < N; j += 256) {
        float2 cp = C2[j];
        float dx = ci.x - cp.x;
        float dy = ci.y - cp.y;
        float d2 = dx * dx + dy * dy;
        float d = sqrtf(fmaxf(d2, 1e-12f));       // match ref boundary exactly
        if (d <= 10.0f) {
            float w = expf(-(d2 / 50.0f));
            int slot = atomicAdd(&s_mcount, 1);
            if (slot < MAXC) { cw[slot] = w; cj[slot] = j; }
        }
    }
    __syncthreads();
    const int M  = min(s_mcount, MAXC);
    const int M4 = (M + 3) & ~3;

    // pad to float4 multiple with -1 (never > any real w, which is > 0)
    if (t < M4 - M) cw[M + t] = -1.0f;
    __syncthreads();

    // ---- pass 2: rank-by-counting. keep iff count(w_m > w_k) < 32 ----
    const int own0 = t;
    const int own1 = t + 256;
    const float my0 = (own0 < M) ? cw[own0] : 0.0f;
    const float my1 = (own1 < M) ? cw[own1] : 0.0f;
    int c0 = 0, c1 = 0;
    for (int m = 0; m < M4; m += 4) {
        float4 v = *(const float4*)&cw[m];        // uniform addr => broadcast
        c0 += (v.x > my0) + (v.y > my0) + (v.z > my0) + (v.w > my0);
        c1 += (v.x > my1) + (v.y > my1) + (v.z > my1) + (v.w > my1);
    }
    if (own0 < M && c0 < 32) {
        int slot = atomicAdd(&s_kcount, 1);
        if (slot < MAXK) { kw[slot] = my0; kj[slot] = cj[own0]; }
    }
    if (own1 < M && c1 < 32) {
        int slot = atomicAdd(&s_kcount, 1);
        if (slot < MAXK) { kw[slot] = my1; kj[slot] = cj[own1]; }
    }
    // generic fallback for M > 512 (dead in practice; MAXC caps at 512)
    for (int k = t + 512; k < M; k += 256) {
        float my = cw[k];
        int c = 0;
        for (int m = 0; m < M; ++m) c += (cw[m] > my);
        if (c < 32) {
            int slot = atomicAdd(&s_kcount, 1);
            if (slot < MAXK) { kw[slot] = my; kj[slot] = cj[k]; }
        }
    }
    __syncthreads();
    const int K = min(s_kcount, MAXK);

    // ---- pass 3: row sum (wave-0 shuffle reduce) + normalize ----
    if (t < 64) {
        float v = (t < K) ? kw[t] : 0.0f;         // K <= 64
        #pragma unroll
        for (int off = 32; off > 0; off >>= 1) v += __shfl_down(v, off);
        if (t == 0) s_sum = fmaxf(v, 1e-8f);      // clip(sum, 1e-8, None)
    }
    __syncthreads();
    if (t < K) kw[t] = kw[t] / s_sum;             // true division as ref
    __syncthreads();

    // ---- pass 4: sparse pooling. thread (d, b-group) -> out[b,i,d] ----
    const int d  = t & 63;     // D == 64
    const int bo = t >> 6;     // 4 b-groups per block
    for (int b = bo; b < B; b += 4) {
        const float* Fb = F + (size_t)b * (size_t)N * 64;
        float acc = 0.0f;
        for (int k = 0; k < K; ++k) {
            acc += kw[k] * Fb[(size_t)kj[k] * 64 + d];  // 256B coalesced per (b,k)
        }
        out[((size_t)b * (size_t)N + (size_t)i) * 64 + d] = acc;
    }
}

extern "C" void kernel_launch(void* const* d_in, const int* in_sizes, int n_in,
                              void* d_out, int out_size, void* d_ws, size_t ws_size,
                              hipStream_t stream)
{
    const float* F = (const float*)d_in[0];   // features [B,N,64] f32
    const float* C = (const float*)d_in[1];   // coordinates [N,2] f32
    float* out = (float*)d_out;               // [B,N,64] f32

    const int N = in_sizes[1] / 2;            // 8192
    const int B = in_sizes[0] / (N * 64);     // 8

    social_pool_kernel<<<N, 256, 0, stream>>>(F, C, out, N, B);
}

// Round 5
// 84.151 us; speedup vs baseline: 2.6504x; 1.8599x over previous
//
#include <hip/hip_runtime.h>
#include <math.h>

// SocialPooling: B=8, N=8192, D=64.
// w_ij = exp(-d2/50) if sqrt(max(d2,1e-12)) <= 10 else 0;
// keep w >= (32nd largest w in row); normalize by clip(row_sum,1e-8);
// out[b,i,d] = sum_j w_ij * F[b,j,d].
//
// R5: spatial binning (10x10 cells of 10.24) cuts pass-1 scan 8192->~740;
// rank on d2 (monotone w/ w) so expf only runs for kept (~33) candidates;
// O(M) histogram select replaces O(M^2) count loop; rows processed in
// binned order + XCD-chunked swizzle for feature-gather L2 locality.
// Kept set provably identical to the R4 kernel (tie-exact).

constexpr int   NCELL  = 10;
constexpr int   NCELL2 = 100;
constexpr int   MAXC   = 512;   // candidates/row: lambda~257, max ~340
constexpr int   MAXK   = 64;    // kept: 32 + boundary ties
constexpr int   NBUCK  = 256;
constexpr float BUCKSC = 2.56f; // d2 in [0,100] -> bucket 0..255 (monotone)
constexpr int   NXCD   = 8;

// cell width 10.24: 1/10.24 = 0.09765625 is EXACT in f32; the 0.24 slack
// over radius=10 makes 3x3 neighborhood coverage immune to fp rounding.
__device__ __forceinline__ int cell_x(float x) {
    int c = (int)(x * 0.09765625f);
    return min(max(c, 0), NCELL - 1);
}
__device__ __forceinline__ int cell_of(float2 c) {
    return cell_x(c.y) * NCELL + cell_x(c.x);
}

// ---- prep kernels: build cell lists in d_ws ----
__global__ void k_zero(int* cnt) {
    int t = threadIdx.x;
    if (t < NCELL2) cnt[t] = 0;
}
__global__ void k_count(const float* __restrict__ C, int* __restrict__ cnt, int N) {
    int j = blockIdx.x * 256 + threadIdx.x;
    if (j < N) atomicAdd(&cnt[cell_of(((const float2*)C)[j])], 1);
}
__global__ void k_scan(const int* __restrict__ cnt, int* __restrict__ start,
                       int* __restrict__ cursor) {
    if (threadIdx.x == 0) {
        int s = 0;
        for (int c = 0; c < NCELL2; ++c) { start[c] = s; cursor[c] = s; s += cnt[c]; }
        start[NCELL2] = s;
    }
}
__global__ void k_scatter(const float* __restrict__ C, int* __restrict__ cursor,
                          float2* __restrict__ bXY, int* __restrict__ bIdx, int N) {
    int j = blockIdx.x * 256 + threadIdx.x;
    if (j < N) {
        float2 c = ((const float2*)C)[j];
        int pos = atomicAdd(&cursor[cell_of(c)], 1);
        bXY[pos] = c;
        bIdx[pos] = j;
    }
}

// ---- main kernel: one block per point, in binned order ----
__global__ __launch_bounds__(256)
void social_pool_main(const float* __restrict__ F,
                      const float2* __restrict__ bXY,
                      const int* __restrict__ bIdx,
                      const int* __restrict__ cellStart,
                      float* __restrict__ out,
                      int N, int B)
{
    // XCD-chunked swizzle (bijective: N % NXCD == 0): consecutive binned
    // (= spatially adjacent) rows land on the same XCD -> L2 gather reuse.
    const int bid = blockIdx.x;
    const int q   = (bid % NXCD) * (N / NXCD) + (bid / NXCD);
    const int t   = threadIdx.x;

    __shared__ float cd2[MAXC];       // candidate d2
    __shared__ int   cjj[MAXC];       // candidate original index
    __shared__ int   hist[NBUCK];     // d2 histogram
    __shared__ int   hcum[NBUCK];     // inclusive cumsum
    __shared__ float blist[32];       // threshold-bucket members
    __shared__ float kw[MAXK];        // kept weights (then normalized)
    __shared__ int   kj[MAXK];        // kept indices
    __shared__ int   s_mcount, s_kcount, s_bn, s_bstar, s_cumexcl;
    __shared__ float s_thr_d2, s_sum;

    if (t == 0) { s_mcount = 0; s_kcount = 0; s_bn = 0; }
    hist[t] = 0;                      // blockDim == NBUCK == 256
    __syncthreads();

    const float2 ci = bXY[q];
    const int    i  = bIdx[q];        // original row index for output
    const int cx = cell_x(ci.x);
    const int cy = cell_x(ci.y);

    // ---- pass 1: scan 3x3 cell neighborhood (x-adjacent cells contiguous) ----
    for (int ry = max(cy - 1, 0); ry <= min(cy + 1, NCELL - 1); ++ry) {
        const int c0 = ry * NCELL + max(cx - 1, 0);
        const int c1 = ry * NCELL + min(cx + 1, NCELL - 1);
        const int s = cellStart[c0], e = cellStart[c1 + 1];
        for (int p = s + t; p < e; p += 256) {
            float2 cp = bXY[p];
            float dx = ci.x - cp.x, dy = ci.y - cp.y;
            float d2 = dx * dx + dy * dy;
            float d = sqrtf(fmaxf(d2, 1e-12f));   // exact ref boundary semantics
            if (d <= 10.0f) {
                int slot = atomicAdd(&s_mcount, 1);
                if (slot < MAXC) { cd2[slot] = d2; cjj[slot] = bIdx[p]; }
            }
        }
    }
    __syncthreads();
    const int M = min(s_mcount, MAXC);

    // owned candidate slots (M <= 512, 256 threads)
    const int k0 = t, k1 = t + 256;

    float thr_d2, thr_w;
    if (M > 32) {
        // ---- pass 2a: histogram on d2 (monotone bucketing) ----
        if (k0 < M) atomicAdd(&hist[min(NBUCK - 1, (int)(cd2[k0] * BUCKSC))], 1);
        if (k1 < M) atomicAdd(&hist[min(NBUCK - 1, (int)(cd2[k1] * BUCKSC))], 1);
        __syncthreads();
        // inclusive cumsum (Hillis-Steele over 256 bins)
        hcum[t] = hist[t];
        __syncthreads();
        #pragma unroll
        for (int off = 1; off < NBUCK; off <<= 1) {
            int v = (t >= off) ? hcum[t - off] : 0;
            __syncthreads();
            hcum[t] += v;
            __syncthreads();
        }
        // bucket containing sorted index 31 (32nd smallest d2)
        {
            int ce = hcum[t] - hist[t];           // exclusive cum for bin t
            if (ce <= 31 && 31 < hcum[t]) { s_bstar = t; s_cumexcl = ce; }
        }
        __syncthreads();
        // ---- pass 2b: gather threshold-bucket members (expected ~1-2) ----
        const int bstar = s_bstar;
        if (k0 < M && min(NBUCK - 1, (int)(cd2[k0] * BUCKSC)) == bstar) {
            int sl = atomicAdd(&s_bn, 1); if (sl < 32) blist[sl] = cd2[k0];
        }
        if (k1 < M && min(NBUCK - 1, (int)(cd2[k1] * BUCKSC)) == bstar) {
            int sl = atomicAdd(&s_bn, 1); if (sl < 32) blist[sl] = cd2[k1];
        }
        __syncthreads();
        // exact in-bucket rank: find value at global sorted index 31
        const int bn = min(s_bn, 32);
        if (t < bn) {
            float mine = blist[t];
            int cl = 0, ceq = 0;
            for (int m = 0; m < bn; ++m) {
                cl  += (blist[m] <  mine);
                ceq += (blist[m] == mine);
            }
            int r = s_cumexcl + cl;
            if (r <= 31 && 31 < r + ceq) s_thr_d2 = mine;  // ties write same value
        }
        __syncthreads();
        thr_d2 = s_thr_d2;
        thr_w  = expf(-(thr_d2 / 50.0f));   // == ref thresh (weak monotonicity)
    } else {
        thr_d2 = 3.4e38f;                   // ref thresh would be 0 -> keep all
        thr_w  = 0.0f;
    }

    // ---- pass 3: keep w >= thr_w over tiny d2-margin superset (tie-exact).
    // d2 > thr_d2 + 1e-4 => w < thr_w by >10 ulp (exp arg gap 2e-6 >> 1.2e-7).
    const float marg = thr_d2 + 1e-4f;
    if (k0 < M && cd2[k0] <= marg) {
        float w = expf(-(cd2[k0] / 50.0f));
        if (w >= thr_w) {
            int sl = atomicAdd(&s_kcount, 1);
            if (sl < MAXK) { kw[sl] = w; kj[sl] = cjj[k0]; }
        }
    }
    if (k1 < M && cd2[k1] <= marg) {
        float w = expf(-(cd2[k1] / 50.0f));
        if (w >= thr_w) {
            int sl = atomicAdd(&s_kcount, 1);
            if (sl < MAXK) { kw[sl] = w; kj[sl] = cjj[k1]; }
        }
    }
    __syncthreads();
    const int K = min(s_kcount, MAXK);

    // row sum (wave-0 shuffle reduce, K <= 64) + normalize
    if (t < 64) {
        float v = (t < K) ? kw[t] : 0.0f;
        #pragma unroll
        for (int off = 32; off > 0; off >>= 1) v += __shfl_down(v, off);
        if (t == 0) s_sum = fmaxf(v, 1e-8f);   // clip(sum, 1e-8, None)
    }
    __syncthreads();
    if (t < K) kw[t] = kw[t] / s_sum;          // true division as ref
    __syncthreads();

    // ---- pass 4: pooling. thread = (d-pair = t&31, b = t>>5); all 8 b at once ----
    const int dp = (t & 31) * 2;               // d, d+1
    const int b  = t >> 5;                     // B == 8
    const float* Fb = F + ((size_t)b * (size_t)N) * 64;
    float acc0 = 0.0f, acc1 = 0.0f;
    for (int k = 0; k < K; ++k) {
        float2 f = *(const float2*)&Fb[(size_t)kj[k] * 64 + dp];
        float w = kw[k];
        acc0 += w * f.x;
        acc1 += w * f.y;
    }
    float2* o = (float2*)&out[((size_t)b * (size_t)N + (size_t)i) * 64 + dp];
    *o = make_float2(acc0, acc1);
}

extern "C" void kernel_launch(void* const* d_in, const int* in_sizes, int n_in,
                              void* d_out, int out_size, void* d_ws, size_t ws_size,
                              hipStream_t stream)
{
    const float* F = (const float*)d_in[0];   // features [B,N,64] f32
    const float* C = (const float*)d_in[1];   // coordinates [N,2] f32
    float* out = (float*)d_out;               // [B,N,64] f32

    const int N = in_sizes[1] / 2;            // 8192
    const int B = in_sizes[0] / (N * 64);     // 8

    // d_ws layout (~100 KB; poisoned 0xAA once, fully rewritten every call)
    char* ws = (char*)d_ws;
    int*    cellCnt    = (int*)(ws + 0);
    int*    cellStart  = (int*)(ws + 512);      // NCELL2+1 entries
    int*    cellCursor = (int*)(ws + 1024);
    float2* bXY        = (float2*)(ws + 1536);  // N float2
    int*    bIdx       = (int*)(ws + 1536 + (size_t)N * 8);

    const int nb = (N + 255) / 256;
    k_zero   <<<1, 128, 0, stream>>>(cellCnt);
    k_count  <<<nb, 256, 0, stream>>>(C, cellCnt, N);
    k_scan   <<<1, 64, 0, stream>>>(cellCnt, cellStart, cellCursor);
    k_scatter<<<nb, 256, 0, stream>>>(C, cellCursor, bXY, bIdx, N);
    social_pool_main<<<N, 256, 0, stream>>>(F, bXY, bIdx, cellStart, out, N, B);
}

// Round 6
// 54.427 us; speedup vs baseline: 4.0979x; 1.5461x over previous
//
#include <hip/hip_runtime.h>
#include <math.h>

// SocialPooling: B=8, N=8192, D=64.
// w_ij = exp(-d2/50) if sqrt(max(d2,1e-12)) <= 10 else 0;
// keep w >= (32nd largest w in row); normalize by clip(row_sum,1e-8);
// out[b,i,d] = sum_j w_ij * F[b,j,d].
//
// R6: one WAVE per row (zero __syncthreads in main kernel). Wave-synchronous
// histogram select: shfl-scan cumsum, ballot+popc compaction (deterministic
// slot order), LDS handoff via wave_barrier+threadfence_block. 4 rows/block,
// 2048 blocks, XCD-chunked swizzle kept. Prep fused into ONE 1-block kernel.
// Selection math identical to R5 (which passed): bucket on d2 (monotone with
// w), exact in-bucket rank, keep w >= thr_w over d2-margin superset.

constexpr int   NCELL  = 10;
constexpr int   NCELL2 = 100;
constexpr int   MAXC   = 448;   // candidates/row: lambda~257, std~16 (+12σ)
constexpr int   MAXK   = 64;    // kept: 32 + boundary ties
constexpr float BUCKSC = 2.56f; // d2 in [0,100] -> bucket 0..255 (monotone)
constexpr int   NXCD   = 8;

// cell width 10.24: 1/10.24 = 0.09765625 EXACT in f32; 0.24 slack makes the
// 3x3 neighborhood cover the radius-10 disc against any fp rounding.
__device__ __forceinline__ int cell_x(float x) {
    int c = (int)(x * 0.09765625f);
    return min(max(c, 0), NCELL - 1);
}
__device__ __forceinline__ int cell_of(float2 c) {
    return cell_x(c.y) * NCELL + cell_x(c.x);
}

// wave-synchronous LDS handoff: block compiler reordering + drain LDS queue.
__device__ __forceinline__ void wsync() {
    __builtin_amdgcn_wave_barrier();
    __threadfence_block();
    __builtin_amdgcn_wave_barrier();
}

// ---- fused prep: zero + count + scan + scatter, one block ----
__global__ __launch_bounds__(1024)
void k_prep(const float* __restrict__ C, int* __restrict__ cellStart,
            float2* __restrict__ bXY, int* __restrict__ bIdx, int N)
{
    __shared__ int h[NCELL2];
    __shared__ int cur[NCELL2];
    const int t = threadIdx.x;
    if (t < NCELL2) h[t] = 0;
    __syncthreads();
    const float2* C2 = (const float2*)C;
    for (int j = t; j < N; j += 1024) atomicAdd(&h[cell_of(C2[j])], 1);
    __syncthreads();
    if (t == 0) {
        int s = 0;
        for (int c = 0; c < NCELL2; ++c) { int n = h[c]; cur[c] = s; cellStart[c] = s; s += n; }
        cellStart[NCELL2] = s;
    }
    __syncthreads();
    for (int j = t; j < N; j += 1024) {
        float2 c = C2[j];
        int pos = atomicAdd(&cur[cell_of(c)], 1);
        bXY[pos] = c; bIdx[pos] = j;
    }
}

// ---- main: one wave per row, 4 rows per block ----
__global__ __launch_bounds__(256)
void social_pool_main(const float* __restrict__ F,
                      const float2* __restrict__ bXY,
                      const int* __restrict__ bIdx,
                      const int* __restrict__ cellStart,
                      float* __restrict__ out, int N, int B)
{
    __shared__ float s_cd2[4][MAXC];
    __shared__ int   s_cjj[4][MAXC];
    __shared__ __align__(16) int s_hist[4][256];
    __shared__ float s_blist[4][32];
    __shared__ float s_kw[4][MAXK];
    __shared__ int   s_kj[4][MAXK];

    const int t = threadIdx.x, wid = t >> 6, lane = t & 63;
    float* cd2   = s_cd2[wid];
    int*   cjj   = s_cjj[wid];
    int*   hist  = s_hist[wid];
    float* blist = s_blist[wid];
    float* kw    = s_kw[wid];
    int*   kj    = s_kj[wid];

    *(int4*)&hist[lane * 4] = make_int4(0, 0, 0, 0);

    // XCD-chunked swizzle (bijective: 2048 % 8 == 0): consecutive binned
    // rows -> same XCD L2 for the feature gather.
    const int bid = blockIdx.x, nb = gridDim.x;
    const int sb = (nb % NXCD == 0) ? (bid % NXCD) * (nb / NXCD) + bid / NXCD : bid;
    const int q = sb * 4 + wid;
    if (q >= N) return;

    const float2 ci = bXY[q];
    const int    i  = bIdx[q];          // original row index for output
    const int cx = cell_x(ci.x), cy = cell_x(ci.y);
    const unsigned long long below = (1ull << lane) - 1ull;

    // ---- pass 1: scan 3x3 cells; ballot+popc compaction (no atomics,
    //      deterministic binned order). Uniform trip counts => no divergence
    //      at the ballot sites.
    int mc = 0;
    for (int ry = max(cy - 1, 0); ry <= min(cy + 1, NCELL - 1); ++ry) {
        const int c0 = ry * NCELL + max(cx - 1, 0);
        const int c1 = ry * NCELL + min(cx + 1, NCELL - 1);
        const int s = cellStart[c0], e = cellStart[c1 + 1];
        for (int p0 = s; p0 < e; p0 += 64) {
            const int p = p0 + lane;
            bool hit = false; float d2 = 0.0f; int jj = 0;
            if (p < e) {
                float2 cp = bXY[p];
                float dx = ci.x - cp.x, dy = ci.y - cp.y;
                d2 = dx * dx + dy * dy;
                float d = sqrtf(fmaxf(d2, 1e-12f));   // exact ref boundary
                if (d <= 10.0f) { hit = true; jj = bIdx[p]; }
            }
            unsigned long long mk = __ballot(hit);
            int off = __popcll(mk & below);
            if (hit && mc + off < MAXC) { cd2[mc + off] = d2; cjj[mc + off] = jj; }
            mc += (int)__popcll(mk);
        }
    }
    wsync();
    const int M = min(mc, MAXC);

    // ---- pass 2: 32nd-smallest d2 via per-wave 256-bin histogram ----
    float thr_d2, thr_w;
    if (M > 32) {
        for (int k = lane; k < M; k += 64)
            atomicAdd(&hist[min(255, (int)(cd2[k] * BUCKSC))], 1);
        wsync();
        // lane owns bins 4l..4l+3; wave-wide inclusive shfl-scan of totals
        int4 h4 = *(const int4*)&hist[lane * 4];
        int hh0 = h4.x, hh1 = h4.y, hh2 = h4.z, hh3 = h4.w;
        int tot = hh0 + hh1 + hh2 + hh3;
        int sc = tot;
        #pragma unroll
        for (int o = 1; o < 64; o <<= 1) {
            int v = __shfl_up(sc, o);
            if (lane >= o) sc += v;
        }
        int ce = sc - tot;                 // exclusive cum at bin 4*lane
        // find the bucket containing sorted index 31
        int fb = -1, fce = 0;
        if (ce <= 31 && 31 < ce + hh0) { fb = lane * 4 + 0; fce = ce; } ce += hh0;
        if (fb < 0 && ce <= 31 && 31 < ce + hh1) { fb = lane * 4 + 1; fce = ce; } ce += hh1;
        if (fb < 0 && ce <= 31 && 31 < ce + hh2) { fb = lane * 4 + 2; fce = ce; } ce += hh2;
        if (fb < 0 && ce <= 31 && 31 < ce + hh3) { fb = lane * 4 + 3; fce = ce; }
        unsigned long long mk1 = __ballot(fb >= 0);
        int src1 = (mk1 != 0ull) ? (__ffsll((unsigned long long)mk1) - 1) : 0;
        const int bstar   = __shfl(fb,  src1);
        const int cumexcl = __shfl(fce, src1);
        // gather threshold-bucket members (expected ~1-2)
        int bn = 0;
        for (int k0 = 0; k0 < M; k0 += 64) {
            const int k = k0 + lane;
            bool inb = (k < M) && (min(255, (int)(cd2[k] * BUCKSC)) == bstar);
            unsigned long long mk = __ballot(inb);
            int off = __popcll(mk & below);
            if (inb && bn + off < 32) blist[bn + off] = cd2[k];
            bn += (int)__popcll(mk);
        }
        wsync();
        bn = min(bn, 32);
        // exact in-bucket rank: value at global sorted index 31
        float mine = 0.0f; int ok = 0;
        if (lane < bn) {
            mine = blist[lane];
            int cl = 0, ceq = 0;
            for (int m = 0; m < bn; ++m) {
                cl  += (blist[m] <  mine);
                ceq += (blist[m] == mine);
            }
            int r = cumexcl + cl;
            ok = (r <= 31 && 31 < r + ceq);
        }
        unsigned long long mk2 = __ballot(ok);
        int src2 = (mk2 != 0ull) ? (__ffsll((unsigned long long)mk2) - 1) : 0;
        thr_d2 = __shfl(mine, src2);
        thr_w  = expf(-(thr_d2 / 50.0f));  // == ref thresh (weak monotonicity)
    } else {
        thr_d2 = 3.4e38f;                  // ref thresh would be 0 -> keep all
        thr_w  = 0.0f;
    }

    // ---- pass 3: keep w >= thr_w over tiny d2-margin superset (tie-exact);
    //      ballot compaction => deterministic kept order.
    const float marg = thr_d2 + 1e-4f;
    int kc = 0;
    for (int k0 = 0; k0 < M; k0 += 64) {
        const int k = k0 + lane;
        bool keep = false; float w = 0.0f; int jj = 0;
        if (k < M && cd2[k] <= marg) {
            w = expf(-(cd2[k] / 50.0f));
            if (w >= thr_w) { keep = true; jj = cjj[k]; }
        }
        unsigned long long mk = __ballot(keep);
        int off = __popcll(mk & below);
        if (keep && kc + off < MAXK) { kw[kc + off] = w; kj[kc + off] = jj; }
        kc += (int)__popcll(mk);
    }
    wsync();
    const int K = min(kc, MAXK);

    // row sum (butterfly, all lanes get it) + normalize
    float v = (lane < K) ? kw[lane] : 0.0f;
    #pragma unroll
    for (int o = 32; o > 0; o >>= 1) v += __shfl_xor(v, o);
    const float ssum = fmaxf(v, 1e-8f);    // clip(sum, 1e-8, None)
    if (lane < K) kw[lane] = kw[lane] / ssum;   // true division as ref
    wsync();

    // ---- pass 4: pooling. lane = dim d; loop k, all 8 batches unrolled.
    //      Per (k,b): 64 lanes x 4B = one 256B coalesced L2 gather.
    const size_t NL = (size_t)N * 64;
    const float* F0 = F + lane;
    float* O0 = out + (size_t)i * 64 + lane;
    if (B == 8) {
        float a0=0,a1=0,a2=0,a3=0,a4=0,a5=0,a6=0,a7=0;
        for (int k = 0; k < K; ++k) {
            const float w = kw[k];
            const float* fp = F0 + (size_t)kj[k] * 64;
            a0 += w * fp[0*NL]; a1 += w * fp[1*NL];
            a2 += w * fp[2*NL]; a3 += w * fp[3*NL];
            a4 += w * fp[4*NL]; a5 += w * fp[5*NL];
            a6 += w * fp[6*NL]; a7 += w * fp[7*NL];
        }
        O0[0*NL]=a0; O0[1*NL]=a1; O0[2*NL]=a2; O0[3*NL]=a3;
        O0[4*NL]=a4; O0[5*NL]=a5; O0[6*NL]=a6; O0[7*NL]=a7;
    } else {
        for (int b = 0; b < B; ++b) {
            float a = 0.0f;
            const float* Fb = F0 + (size_t)b * NL;
            for (int k = 0; k < K; ++k)
                a += kw[k] * Fb[(size_t)kj[k] * 64];
            O0[(size_t)b * NL] = a;
        }
    }
}

extern "C" void kernel_launch(void* const* d_in, const int* in_sizes, int n_in,
                              void* d_out, int out_size, void* d_ws, size_t ws_size,
                              hipStream_t stream)
{
    const float* F = (const float*)d_in[0];   // features [B,N,64] f32
    const float* C = (const float*)d_in[1];   // coordinates [N,2] f32
    float* out = (float*)d_out;               // [B,N,64] f32

    const int N = in_sizes[1] / 2;            // 8192
    const int B = in_sizes[0] / (N * 64);     // 8

    // d_ws layout (~97 KB; fully rewritten every call)
    char* ws = (char*)d_ws;
    int*    cellStart = (int*)(ws + 0);                   // NCELL2+1 ints
    float2* bXY       = (float2*)(ws + 512);              // N float2
    int*    bIdx      = (int*)(ws + 512 + (size_t)N * 8); // N ints

    k_prep<<<1, 1024, 0, stream>>>(C, cellStart, bXY, bIdx, N);
    social_pool_main<<<(N + 3) / 4, 256, 0, stream>>>(F, bXY, bIdx, cellStart, out, N, B);
}

// Round 7
// 51.385 us; speedup vs baseline: 4.3406x; 1.0592x over previous
//
#include <hip/hip_runtime.h>
#include <math.h>

// SocialPooling: B=8, N=8192, D=64.
// w_ij = exp(-d2/50) if sqrt(max(d2,1e-12)) <= 10 else 0;
// keep w >= (32nd largest w in row); normalize by clip(row_sum,1e-8);
// out[b,i,d] = sum_j w_ij * F[b,j,d].
//
// R7 (selection math identical to passing R6):
//  - LDS/block 20992 -> 19968 B (MAXC 416, kw/kj fused to float2) => 8
//    blocks/CU resident (was 7+1 serial tail).
//  - Templated N=8192,B=8 fast path => constant strides, SGPR-base addressing.
//  - Pass 4: lane=(d-quad,b-pair), 2x global_load_dwordx4 + 1x ds_read_b64
//    per k, unroll 2 => ~250 instr (was ~640 + 64-bit addr chains).
//  - Prep: parallel Hillis-Steele scan replaces serial 100-iter loop.

constexpr int   NCELL  = 10;
constexpr int   NCELL2 = 100;
constexpr int   MAXC   = 416;   // candidates/row: lambda~257, std~16 (+10σ)
constexpr int   MAXK   = 64;    // kept: 32 + boundary ties
constexpr float BUCKSC = 2.56f; // d2 in [0,100] -> bucket 0..255 (monotone)
constexpr int   NXCD   = 8;

// cell width 10.24: 1/10.24 = 0.09765625 EXACT in f32; 0.24 slack makes the
// 3x3 neighborhood cover the radius-10 disc against any fp rounding.
__device__ __forceinline__ int cell_x(float x) {
    int c = (int)(x * 0.09765625f);
    return min(max(c, 0), NCELL - 1);
}
__device__ __forceinline__ int cell_of(float2 c) {
    return cell_x(c.y) * NCELL + cell_x(c.x);
}

// wave-synchronous LDS handoff (proven in R6)
__device__ __forceinline__ void wsync() {
    __builtin_amdgcn_wave_barrier();
    __threadfence_block();
    __builtin_amdgcn_wave_barrier();
}

// ---- fused prep: zero + count + parallel scan + scatter, one block ----
__global__ __launch_bounds__(1024)
void k_prep(const float* __restrict__ C, int* __restrict__ cellStart,
            float2* __restrict__ bXY, int* __restrict__ bIdx, int N)
{
    __shared__ int h[128];
    __shared__ int cur[NCELL2];
    const int t = threadIdx.x;
    if (t < 128) h[t] = 0;
    __syncthreads();
    const float2* C2 = (const float2*)C;
    for (int j = t; j < N; j += 1024) atomicAdd(&h[cell_of(C2[j])], 1);
    __syncthreads();
    // inclusive Hillis-Steele scan over 128 slots (barriers block-uniform)
    #pragma unroll
    for (int o = 1; o < 128; o <<= 1) {
        int u = (t < 128 && t >= o) ? h[t - o] : 0;
        __syncthreads();
        if (t < 128) h[t] += u;
        __syncthreads();
    }
    if (t < NCELL2) {
        int s = (t == 0) ? 0 : h[t - 1];      // exclusive prefix
        cur[t] = s; cellStart[t] = s;
        if (t == 0) cellStart[NCELL2] = h[NCELL2 - 1];
    }
    __syncthreads();
    for (int j = t; j < N; j += 1024) {
        float2 c = C2[j];
        int pos = atomicAdd(&cur[cell_of(c)], 1);
        bXY[pos] = c; bIdx[pos] = j;
    }
}

// ---- main: one wave per row, 4 rows per block, 19968 B LDS ----
template<int TN, int TB>
__global__ __launch_bounds__(256, 8)   // pin VGPR<=64 => 8 blocks/CU
void social_pool_main(const float* __restrict__ F,
                      const float2* __restrict__ bXY,
                      const int* __restrict__ bIdx,
                      const int* __restrict__ cellStart,
                      float* __restrict__ out, int Nrt, int Brt)
{
    const int N = (TN > 0) ? TN : Nrt;
    const int B = (TB > 0) ? TB : Brt;

    __shared__ float  s_cd2[4][MAXC];
    __shared__ int    s_cjj[4][MAXC];
    __shared__ __align__(16) int s_hist[4][256];
    __shared__ float  s_blist[4][32];
    __shared__ float2 s_kwj[4][MAXK];   // (w, bitcast j) pairs

    const int t = threadIdx.x, wid = t >> 6, lane = t & 63;
    float*  cd2   = s_cd2[wid];
    int*    cjj   = s_cjj[wid];
    int*    hist  = s_hist[wid];
    float*  blist = s_blist[wid];
    float2* kwj   = s_kwj[wid];

    *(int4*)&hist[lane * 4] = make_int4(0, 0, 0, 0);

    // XCD-chunked swizzle (bijective: nb % 8 == 0): consecutive binned rows
    // -> same XCD L2 for the feature gather.
    const int bid = blockIdx.x, nb = gridDim.x;
    const int sb = (nb % NXCD == 0) ? (bid % NXCD) * (nb / NXCD) + bid / NXCD : bid;
    const int q = sb * 4 + wid;
    if (q >= N) return;

    const float2 ci = bXY[q];
    const int    i  = bIdx[q];          // original row index for output
    const int cx = cell_x(ci.x), cy = cell_x(ci.y);
    const unsigned long long below = (1ull << lane) - 1ull;

    // ---- pass 1: scan 3x3 cells; ballot+popc compaction ----
    int mc = 0;
    for (int ry = max(cy - 1, 0); ry <= min(cy + 1, NCELL - 1); ++ry) {
        const int c0 = ry * NCELL + max(cx - 1, 0);
        const int c1 = ry * NCELL + min(cx + 1, NCELL - 1);
        const int s = cellStart[c0], e = cellStart[c1 + 1];
        for (int p0 = s; p0 < e; p0 += 64) {
            const int p = p0 + lane;
            bool hit = false; float d2 = 0.0f; int jj = 0;
            if (p < e) {
                float2 cp = bXY[p];
                float dx = ci.x - cp.x, dy = ci.y - cp.y;
                d2 = dx * dx + dy * dy;
                float d = sqrtf(fmaxf(d2, 1e-12f));   // exact ref boundary
                if (d <= 10.0f) { hit = true; jj = bIdx[p]; }
            }
            unsigned long long mk = __ballot(hit);
            int off = __popcll(mk & below);
            if (hit && mc + off < MAXC) { cd2[mc + off] = d2; cjj[mc + off] = jj; }
            mc += (int)__popcll(mk);
        }
    }
    wsync();
    const int M = min(mc, MAXC);

    // ---- pass 2: 32nd-smallest d2 via per-wave 256-bin histogram ----
    float thr_d2, thr_w;
    if (M > 32) {
        for (int k = lane; k < M; k += 64)
            atomicAdd(&hist[min(255, (int)(cd2[k] * BUCKSC))], 1);
        wsync();
        int4 h4 = *(const int4*)&hist[lane * 4];
        int hh0 = h4.x, hh1 = h4.y, hh2 = h4.z, hh3 = h4.w;
        int tot = hh0 + hh1 + hh2 + hh3;
        int sc = tot;
        #pragma unroll
        for (int o = 1; o < 64; o <<= 1) {
            int v = __shfl_up(sc, o);
            if (lane >= o) sc += v;
        }
        int ce = sc - tot;                 // exclusive cum at bin 4*lane
        int fb = -1, fce = 0;
        if (ce <= 31 && 31 < ce + hh0) { fb = lane * 4 + 0; fce = ce; } ce += hh0;
        if (fb < 0 && ce <= 31 && 31 < ce + hh1) { fb = lane * 4 + 1; fce = ce; } ce += hh1;
        if (fb < 0 && ce <= 31 && 31 < ce + hh2) { fb = lane * 4 + 2; fce = ce; } ce += hh2;
        if (fb < 0 && ce <= 31 && 31 < ce + hh3) { fb = lane * 4 + 3; fce = ce; }
        unsigned long long mk1 = __ballot(fb >= 0);
        int src1 = (mk1 != 0ull) ? (__ffsll((unsigned long long)mk1) - 1) : 0;
        const int bstar   = __shfl(fb,  src1);
        const int cumexcl = __shfl(fce, src1);
        // gather threshold-bucket members (expected ~1-2)
        int bn = 0;
        for (int k0 = 0; k0 < M; k0 += 64) {
            const int k = k0 + lane;
            bool inb = (k < M) && (min(255, (int)(cd2[k] * BUCKSC)) == bstar);
            unsigned long long mk = __ballot(inb);
            int off = __popcll(mk & below);
            if (inb && bn + off < 32) blist[bn + off] = cd2[k];
            bn += (int)__popcll(mk);
        }
        wsync();
        bn = min(bn, 32);
        float mine = 0.0f; int ok = 0;
        if (lane < bn) {
            mine = blist[lane];
            int cl = 0, ceq = 0;
            for (int m = 0; m < bn; ++m) {
                cl  += (blist[m] <  mine);
                ceq += (blist[m] == mine);
            }
            int r = cumexcl + cl;
            ok = (r <= 31 && 31 < r + ceq);
        }
        unsigned long long mk2 = __ballot(ok);
        int src2 = (mk2 != 0ull) ? (__ffsll((unsigned long long)mk2) - 1) : 0;
        thr_d2 = __shfl(mine, src2);
        thr_w  = expf(-(thr_d2 / 50.0f));  // == ref thresh (weak monotonicity)
    } else {
        thr_d2 = 3.4e38f;                  // ref thresh would be 0 -> keep all
        thr_w  = 0.0f;
    }

    // ---- pass 3: keep w >= thr_w over d2-margin superset (tie-exact) ----
    const float marg = thr_d2 + 1e-4f;
    int kc = 0;
    for (int k0 = 0; k0 < M; k0 += 64) {
        const int k = k0 + lane;
        bool keep = false; float w = 0.0f; int jj = 0;
        if (k < M && cd2[k] <= marg) {
            w = expf(-(cd2[k] / 50.0f));
            if (w >= thr_w) { keep = true; jj = cjj[k]; }
        }
        unsigned long long mk = __ballot(keep);
        int off = __popcll(mk & below);
        if (keep && kc + off < MAXK)
            kwj[kc + off] = make_float2(w, __int_as_float(jj));
        kc += (int)__popcll(mk);
    }
    wsync();
    const int K = min(kc, MAXK);

    // row sum (butterfly) + normalize
    float v = (lane < K) ? kwj[lane].x : 0.0f;
    #pragma unroll
    for (int o = 32; o > 0; o >>= 1) v += __shfl_xor(v, o);
    const float ssum = fmaxf(v, 1e-8f);         // clip(sum, 1e-8, None)
    if (lane < K) kwj[lane].x = kwj[lane].x / ssum;  // true division as ref
    wsync();

    // ---- pass 4: pooling ----
    const size_t NL = (size_t)N * 64;
    if (TB == 8) {
        // lane = (d-quad dq, batch-pair bp): 2x dwordx4 loads + 8 FMA per k.
        const int dq = (lane & 15) * 4;
        const int bp = (lane >> 4) * 2;
        const float* Fb0 = F + (size_t)bp * NL + dq;
        const float* Fb1 = Fb0 + NL;
        float4 a0 = make_float4(0.f, 0.f, 0.f, 0.f);
        float4 a1 = make_float4(0.f, 0.f, 0.f, 0.f);
        #pragma unroll 2
        for (int k = 0; k < K; ++k) {
            float2 wj = kwj[k];                  // ds_read_b64 broadcast
            const float w = wj.x;
            const size_t o = (size_t)__float_as_int(wj.y) * 64;
            float4 f0 = *(const float4*)(Fb0 + o);
            float4 f1 = *(const float4*)(Fb1 + o);
            a0.x += w * f0.x; a0.y += w * f0.y; a0.z += w * f0.z; a0.w += w * f0.w;
            a1.x += w * f1.x; a1.y += w * f1.y; a1.z += w * f1.z; a1.w += w * f1.w;
        }
        float* O0 = out + (size_t)bp * NL + (size_t)i * 64 + dq;
        *(float4*)O0 = a0;
        *(float4*)(O0 + NL) = a1;
    } else {
        const float* F0 = F + lane;
        float* O0 = out + (size_t)i * 64 + lane;
        for (int b = 0; b < B; ++b) {
            float a = 0.0f;
            const float* Fb = F0 + (size_t)b * NL;
            for (int k = 0; k < K; ++k) {
                float2 wj = kwj[k];
                a += wj.x * Fb[(size_t)__float_as_int(wj.y) * 64];
            }
            O0[(size_t)b * NL] = a;
        }
    }
}

extern "C" void kernel_launch(void* const* d_in, const int* in_sizes, int n_in,
                              void* d_out, int out_size, void* d_ws, size_t ws_size,
                              hipStream_t stream)
{
    const float* F = (const float*)d_in[0];   // features [B,N,64] f32
    const float* C = (const float*)d_in[1];   // coordinates [N,2] f32
    float* out = (float*)d_out;               // [B,N,64] f32

    const int N = in_sizes[1] / 2;            // 8192
    const int B = in_sizes[0] / (N * 64);     // 8

    // d_ws layout (~97 KB; fully rewritten every call)
    char* ws = (char*)d_ws;
    int*    cellStart = (int*)(ws + 0);                   // NCELL2+1 ints
    float2* bXY       = (float2*)(ws + 512);              // N float2
    int*    bIdx      = (int*)(ws + 512 + (size_t)N * 8); // N ints

    k_prep<<<1, 1024, 0, stream>>>(C, cellStart, bXY, bIdx, N);
    if (N == 8192 && B == 8)
        social_pool_main<8192, 8><<<2048, 256, 0, stream>>>(F, bXY, bIdx, cellStart, out, N, B);
    else
        social_pool_main<0, 0><<<(N + 3) / 4, 256, 0, stream>>>(F, bXY, bIdx, cellStart, out, N, B);
}

// Round 8
// 50.711 us; speedup vs baseline: 4.3982x; 1.0133x over previous
//
#include <hip/hip_runtime.h>
#include <math.h>

// SocialPooling: B=8, N=8192, D=64.
// w_ij = exp(-d2/50) if sqrt(max(d2,1e-12)) <= 10 else 0;
// keep w >= (32nd largest w in row); normalize by clip(row_sum,1e-8);
// out[b,i,d] = sum_j w_ij * F[b,j,d].
//
// R8 (selection math bit-identical to passing R7):
//  - Row->block decorrelation: within each XCD 1024-row chunk, a block's 4
//    waves take rows {l, l+256, l+512, l+768}. Blocks/CUs get iid density
//    samples => completion tail compressed (R7: grid==capacity, occupancy
//    decayed to 54.8% = pure tail). XCD-L2 gather locality preserved.
//  - Pass 4: register normalize + readlane broadcast (k is SGPR-uniform) =>
//    no ds_read in the gather chain, scalar-base addressing.
//  - wsync drains lgkmcnt only (LDS is wave-private; no vmcnt(0) drain).
//  - Pass 1 stores candidate position p; bIdx resolved only for ~33 kept.

constexpr int   NCELL  = 10;
constexpr int   NCELL2 = 100;
constexpr int   MAXC   = 416;   // candidates/row: lambda~257, std~16 (+10σ)
constexpr int   MAXK   = 64;    // kept: 32 + boundary ties
constexpr float BUCKSC = 2.56f; // d2 in [0,100] -> bucket 0..255 (monotone)
constexpr int   NXCD   = 8;

// cell width 10.24: 1/10.24 = 0.09765625 EXACT in f32; 0.24 slack makes the
// 3x3 neighborhood cover the radius-10 disc against any fp rounding.
__device__ __forceinline__ int cell_x(float x) {
    int c = (int)(x * 0.09765625f);
    return min(max(c, 0), NCELL - 1);
}
__device__ __forceinline__ int cell_of(float2 c) {
    return cell_x(c.y) * NCELL + cell_x(c.x);
}

// wave-synchronous LDS handoff: LDS here is wave-private, so only the LDS
// queue (lgkmcnt) needs draining — not outstanding global loads (vmcnt).
__device__ __forceinline__ void wsync() {
    __builtin_amdgcn_wave_barrier();
    asm volatile("s_waitcnt lgkmcnt(0)" ::: "memory");
    __builtin_amdgcn_wave_barrier();
}

// ---- fused prep: zero + count + parallel scan + scatter, one block ----
__global__ __launch_bounds__(1024)
void k_prep(const float* __restrict__ C, int* __restrict__ cellStart,
            float2* __restrict__ bXY, int* __restrict__ bIdx, int N)
{
    __shared__ int h[128];
    __shared__ int cur[NCELL2];
    const int t = threadIdx.x;
    if (t < 128) h[t] = 0;
    __syncthreads();
    const float2* C2 = (const float2*)C;
    for (int j = t; j < N; j += 1024) atomicAdd(&h[cell_of(C2[j])], 1);
    __syncthreads();
    #pragma unroll
    for (int o = 1; o < 128; o <<= 1) {
        int u = (t < 128 && t >= o) ? h[t - o] : 0;
        __syncthreads();
        if (t < 128) h[t] += u;
        __syncthreads();
    }
    if (t < NCELL2) {
        int s = (t == 0) ? 0 : h[t - 1];      // exclusive prefix
        cur[t] = s; cellStart[t] = s;
        if (t == 0) cellStart[NCELL2] = h[NCELL2 - 1];
    }
    __syncthreads();
    for (int j = t; j < N; j += 1024) {
        float2 c = C2[j];
        int pos = atomicAdd(&cur[cell_of(c)], 1);
        bXY[pos] = c; bIdx[pos] = j;
    }
}

// ---- main: one wave per row, 4 rows per block, 19968 B LDS ----
template<int TN, int TB>
__global__ __launch_bounds__(256, 8)   // pin VGPR<=64 => 8 blocks/CU
void social_pool_main(const float* __restrict__ F,
                      const float2* __restrict__ bXY,
                      const int* __restrict__ bIdx,
                      const int* __restrict__ cellStart,
                      float* __restrict__ out, int Nrt, int Brt)
{
    const int N = (TN > 0) ? TN : Nrt;
    const int B = (TB > 0) ? TB : Brt;

    __shared__ float  s_cd2[4][MAXC];
    __shared__ int    s_cjj[4][MAXC];
    __shared__ __align__(16) int s_hist[4][256];
    __shared__ float  s_blist[4][32];
    __shared__ float2 s_kwj[4][MAXK];   // (w, bitcast j) compaction buffer

    const int t = threadIdx.x, wid = t >> 6, lane = t & 63;
    float*  cd2   = s_cd2[wid];
    int*    cjj   = s_cjj[wid];
    int*    hist  = s_hist[wid];
    float*  blist = s_blist[wid];
    float2* kwj   = s_kwj[wid];

    *(int4*)&hist[lane * 4] = make_int4(0, 0, 0, 0);

    // Row mapping. Fast path: chunk = bid%8 (XCD under round-robin dispatch)
    // owns rows [chunk*1024, chunk*1024+1024); block l = bid/8 takes rows
    // {l, l+256, l+512, l+768} (stride-256 across its 4 waves) => block/CU
    // workloads are iid density samples; L2 locality kept (same chunk).
    const int bid = blockIdx.x, nb = gridDim.x;
    int q;
    if (TN > 0) {
        q = (bid & 7) * 1024 + wid * 256 + (bid >> 3);
    } else {
        const int sb = (nb % NXCD == 0) ? (bid % NXCD) * (nb / NXCD) + bid / NXCD : bid;
        q = sb * 4 + wid;
    }
    if (q >= N) return;

    const float2 ci = bXY[q];
    const int    i  = bIdx[q];          // original row index for output
    const int cx = cell_x(ci.x), cy = cell_x(ci.y);
    const unsigned long long below = (1ull << lane) - 1ull;

    // ---- pass 1: scan 3x3 cells; ballot+popc compaction; store position p ----
    int mc = 0;
    for (int ry = max(cy - 1, 0); ry <= min(cy + 1, NCELL - 1); ++ry) {
        const int c0 = ry * NCELL + max(cx - 1, 0);
        const int c1 = ry * NCELL + min(cx + 1, NCELL - 1);
        const int s = cellStart[c0], e = cellStart[c1 + 1];
        for (int p0 = s; p0 < e; p0 += 64) {
            const int p = p0 + lane;
            bool hit = false; float d2 = 0.0f;
            if (p < e) {
                float2 cp = bXY[p];
                float dx = ci.x - cp.x, dy = ci.y - cp.y;
                d2 = dx * dx + dy * dy;
                float d = sqrtf(fmaxf(d2, 1e-12f));   // exact ref boundary
                hit = (d <= 10.0f);
            }
            unsigned long long mk = __ballot(hit);
            int off = __popcll(mk & below);
            if (hit && mc + off < MAXC) { cd2[mc + off] = d2; cjj[mc + off] = p; }
            mc += (int)__popcll(mk);
        }
    }
    wsync();
    const int M = min(mc, MAXC);

    // ---- pass 2: 32nd-smallest d2 via per-wave 256-bin histogram ----
    float thr_d2, thr_w;
    if (M > 32) {
        for (int k = lane; k < M; k += 64)
            atomicAdd(&hist[min(255, (int)(cd2[k] * BUCKSC))], 1);
        wsync();
        int4 h4 = *(const int4*)&hist[lane * 4];
        int hh0 = h4.x, hh1 = h4.y, hh2 = h4.z, hh3 = h4.w;
        int tot = hh0 + hh1 + hh2 + hh3;
        int sc = tot;
        #pragma unroll
        for (int o = 1; o < 64; o <<= 1) {
            int v = __shfl_up(sc, o);
            if (lane >= o) sc += v;
        }
        int ce = sc - tot;                 // exclusive cum at bin 4*lane
        int fb = -1, fce = 0;
        if (ce <= 31 && 31 < ce + hh0) { fb = lane * 4 + 0; fce = ce; } ce += hh0;
        if (fb < 0 && ce <= 31 && 31 < ce + hh1) { fb = lane * 4 + 1; fce = ce; } ce += hh1;
        if (fb < 0 && ce <= 31 && 31 < ce + hh2) { fb = lane * 4 + 2; fce = ce; } ce += hh2;
        if (fb < 0 && ce <= 31 && 31 < ce + hh3) { fb = lane * 4 + 3; fce = ce; }
        unsigned long long mk1 = __ballot(fb >= 0);
        int src1 = (mk1 != 0ull) ? (__ffsll((unsigned long long)mk1) - 1) : 0;
        const int bstar   = __shfl(fb,  src1);
        const int cumexcl = __shfl(fce, src1);
        // gather threshold-bucket members (expected ~1-2)
        int bn = 0;
        for (int k0 = 0; k0 < M; k0 += 64) {
            const int k = k0 + lane;
            bool inb = (k < M) && (min(255, (int)(cd2[k] * BUCKSC)) == bstar);
            unsigned long long mk = __ballot(inb);
            int off = __popcll(mk & below);
            if (inb && bn + off < 32) blist[bn + off] = cd2[k];
            bn += (int)__popcll(mk);
        }
        wsync();
        bn = min(bn, 32);
        float mine = 0.0f; int ok = 0;
        if (lane < bn) {
            mine = blist[lane];
            int cl = 0, ceq = 0;
            for (int m = 0; m < bn; ++m) {
                cl  += (blist[m] <  mine);
                ceq += (blist[m] == mine);
            }
            int r = cumexcl + cl;
            ok = (r <= 31 && 31 < r + ceq);
        }
        unsigned long long mk2 = __ballot(ok);
        int src2 = (mk2 != 0ull) ? (__ffsll((unsigned long long)mk2) - 1) : 0;
        thr_d2 = __shfl(mine, src2);
        thr_w  = expf(-(thr_d2 / 50.0f));  // == ref thresh (weak monotonicity)
    } else {
        thr_d2 = 3.4e38f;                  // ref thresh would be 0 -> keep all
        thr_w  = 0.0f;
    }

    // ---- pass 3: keep w >= thr_w over d2-margin superset (tie-exact);
    //      resolve bIdx only for kept lanes (~33 loads/wave).
    const float marg = thr_d2 + 1e-4f;
    int kc = 0;
    for (int k0 = 0; k0 < M; k0 += 64) {
        const int k = k0 + lane;
        bool keep = false; float w = 0.0f; int jj = 0;
        if (k < M && cd2[k] <= marg) {
            w = expf(-(cd2[k] / 50.0f));
            if (w >= thr_w) { keep = true; jj = bIdx[cjj[k]]; }
        }
        unsigned long long mk = __ballot(keep);
        int off = __popcll(mk & below);
        if (keep && kc + off < MAXK)
            kwj[kc + off] = make_float2(w, __int_as_float(jj));
        kc += (int)__popcll(mk);
    }
    wsync();
    const int K = min(kc, MAXK);

    // ---- normalize in registers: lane l holds pair l ----
    float2 pr = make_float2(0.0f, 0.0f);
    if (lane < K) pr = kwj[lane];
    float v = pr.x;                        // 0 for lane >= K
    #pragma unroll
    for (int o = 32; o > 0; o >>= 1) v += __shfl_xor(v, o);
    const float ssum = fmaxf(v, 1e-8f);    // clip(sum, 1e-8, None)
    const float wn = pr.x / ssum;          // true division as ref
    const int   jn = __float_as_int(pr.y);
    const int   wi = __float_as_int(wn);

    // ---- pass 4: pooling. readlane(k) -> (w,j) in SGPRs: scalar-base
    //      addressing, no LDS in the gather chain. Accumulation order per
    //      output element identical to R7 (k ascending).
    const size_t NL = (size_t)N * 64;
    if (TB == 8) {
        const int dq = (lane & 15) * 4;
        const int bp = (lane >> 4) * 2;
        const float* Fb0 = F + (size_t)bp * NL + dq;
        const float* Fb1 = Fb0 + NL;
        float4 a0 = make_float4(0.f, 0.f, 0.f, 0.f);
        float4 a1 = make_float4(0.f, 0.f, 0.f, 0.f);
        #pragma unroll 2
        for (int k = 0; k < K; ++k) {
            const float w = __int_as_float(__builtin_amdgcn_readlane(wi, k));
            const size_t o = (size_t)__builtin_amdgcn_readlane(jn, k) * 64;
            float4 f0 = *(const float4*)(Fb0 + o);
            float4 f1 = *(const float4*)(Fb1 + o);
            a0.x += w * f0.x; a0.y += w * f0.y; a0.z += w * f0.z; a0.w += w * f0.w;
            a1.x += w * f1.x; a1.y += w * f1.y; a1.z += w * f1.z; a1.w += w * f1.w;
        }
        float* O0 = out + (size_t)bp * NL + (size_t)i * 64 + dq;
        *(float4*)O0 = a0;
        *(float4*)(O0 + NL) = a1;
    } else {
        const float* F0 = F + lane;
        float* O0 = out + (size_t)i * 64 + lane;
        for (int b = 0; b < B; ++b) {
            float a = 0.0f;
            const float* Fb = F0 + (size_t)b * NL;
            for (int k = 0; k < K; ++k) {
                const float w = __int_as_float(__builtin_amdgcn_readlane(wi, k));
                const size_t o = (size_t)__builtin_amdgcn_readlane(jn, k) * 64;
                a += w * Fb[o];
            }
            O0[(size_t)b * NL] = a;
        }
    }
}

extern "C" void kernel_launch(void* const* d_in, const int* in_sizes, int n_in,
                              void* d_out, int out_size, void* d_ws, size_t ws_size,
                              hipStream_t stream)
{
    const float* F = (const float*)d_in[0];   // features [B,N,64] f32
    const float* C = (const float*)d_in[1];   // coordinates [N,2] f32
    float* out = (float*)d_out;               // [B,N,64] f32

    const int N = in_sizes[1] / 2;            // 8192
    const int B = in_sizes[0] / (N * 64);     // 8

    // d_ws layout (~97 KB; fully rewritten every call)
    char* ws = (char*)d_ws;
    int*    cellStart = (int*)(ws + 0);                   // NCELL2+1 ints
    float2* bXY       = (float2*)(ws + 512);              // N float2
    int*    bIdx      = (int*)(ws + 512 + (size_t)N * 8); // N ints

    k_prep<<<1, 1024, 0, stream>>>(C, cellStart, bXY, bIdx, N);
    if (N == 8192 && B == 8)
        social_pool_main<8192, 8><<<2048, 256, 0, stream>>>(F, bXY, bIdx, cellStart, out, N, B);
    else
        social_pool_main<0, 0><<<(N + 3) / 4, 256, 0, stream>>>(F, bXY, bIdx, cellStart, out, N, B);
}